// Round 4
// baseline (468.519 us; speedup 1.0000x reference)
//
#include <hip/hip_runtime.h>

#define DIM 4096
#define BM 256
#define BN 256
#define BK 64
#define NT (DIM / BK)      // 64 K-tiles
#define THREADS 512        // 8 waves: 2 (M) x 4 (N)

typedef _Float16 half8 __attribute__((ext_vector_type(8)));
typedef _Float16 half4v __attribute__((ext_vector_type(4)));
typedef float floatx16 __attribute__((ext_vector_type(16)));

// Async global->LDS, 16B per lane. LDS dest is wave-uniform base + lane*16.
__device__ __forceinline__ void async_copy16(const _Float16* g, _Float16* l) {
    __builtin_amdgcn_global_load_lds(
        (const __attribute__((address_space(1))) void*)g,
        (__attribute__((address_space(3))) void*)l,
        16, 0, 0);
}

__device__ __forceinline__ void cfence() { asm volatile("" ::: "memory"); }
__device__ __forceinline__ void bar() { cfence(); __builtin_amdgcn_s_barrier(); cfence(); }
#define SB0() __builtin_amdgcn_sched_barrier(0)
#define MFMA32(a_, b_, c_) __builtin_amdgcn_mfma_f32_32x32x16_f16((a_), (b_), (c_), 0, 0, 0)

// 256x256 tile, BK=64, 8-phase schedule, 32x32x16 MFMA, counted vmcnt.
// LDS: [dbuf][A/B][half(128x64)] = 128 KiB. 3-bit XOR swizzle (chunk ^ (row&7))
// -> 0 bank conflicts (verified round 2). global_load_lds writes linearly, so
// the global source is pre-swizzled and ds_read applies the same involution.
//
// Per-wave output 128x64 = 4(M) x 2(N) tiles of 32x32. Per K-tile (4 ksteps of
// 16), phases = balanced m201 pattern (reads 12/4/8/0):
//   ph1: reads aF(mi=0,1)+bF(nj=0) [12]; stage A1(T+1)->lds[ns];
//        lgkm(8); bar; lgkm(0); 8 MFMA (acc[0..1][0]); bar
//   ph2: reads bF(nj=1) [4]; bar; lgkm(0); 8 MFMA (acc[0..1][1]); bar
//   ph3: reads aF(mi=2,3) [8]; stage B0,B1(T+2)->lds[s] (B fully read @ph2);
//        bar; lgkm(0); 8 MFMA (acc[2..3][0]); bar
//   ph4: stage A0(T+2)->lds[s] (A0 fully read @ph3); bar; 8 MFMA
//        (acc[2..3][1]); vmcnt(6); bar
// vmcnt(6): at tile end 14 loads outstanding; retire 8 oldest = all of K(T+1);
// K(T+2) minus A1 (6 loads) stays in flight. Never drained mid-loop.
template <bool QUANT>
__global__ __launch_bounds__(THREADS, 2)
void gemm_bt(const _Float16* __restrict__ A,
             const _Float16* __restrict__ B,
             const float* __restrict__ cb,
             _Float16* __restrict__ Yq,
             float* __restrict__ C)
{
    __shared__ _Float16 lds[2][2][2][128 * BK];   // 128 KiB
    __shared__ float    s_bnd[15];
    __shared__ _Float16 s_cb[16];

    const int t    = threadIdx.x;
    const int lane = t & 63;
    const int wid  = t >> 6;            // 0..7
    const int wm   = (wid >> 2) * 128;  // wave M origin in tile
    const int wn   = (wid & 3) * 64;    // wave N origin in tile
    const int am   = wid >> 2;          // A half this wave reads
    const int bh   = (wid >> 1) & 1;    // B half this wave reads
    const int bro  = (wid & 1) * 64;    // row offset inside B half

    // XCD-aware bijective swizzle (nwg = 256, 256 % 8 == 0)
    const int bid = blockIdx.y * gridDim.x + blockIdx.x;
    const int swz = (bid & 7) * (256 / 8) + (bid >> 3);
    const int bm  = (swz & 15) * BM;
    const int bn  = (swz >> 4) * BN;

    if (QUANT) {
        if (t < 16) s_cb[t]  = (_Float16)cb[t];
        if (t < 15) s_bnd[t] = 0.5f * (cb[t] + cb[t + 1]);
    }

    // Staging: one 128x64 half-tile = 1024 16B chunks; thread t owns physical
    // chunks t and 512+t. Physical chunk p holds logical (row = p>>3,
    // col = (p&7) ^ ((p>>3)&7)) -> pre-swizzle the global source.
    const int pc0 = t, pc1 = 512 + t;
    const int goff0 = (pc0 >> 3) * DIM + ((pc0 & 7) ^ ((pc0 >> 3) & 7)) * 8;  // halves
    const int goff1 = (pc1 >> 3) * DIM + ((pc1 & 7) ^ ((pc1 >> 3) & 7)) * 8;

    auto stage = [&](const _Float16* srcrow0, _Float16* dst) {
        async_copy16(srcrow0 + goff0, dst + t * 8);
        async_copy16(srcrow0 + goff1, dst + (512 + t) * 8);
    };

    // MFMA 32x32x16 f16 fragment: elem[k = (lane>>5)*8 + j] of row (lane&31)
    // (standard doubling of the 32x32x8 mapping). Swizzle inverse on read:
    // physical 16B chunk = (ks*2 + khalf) ^ (row&7); row&7 == lane&7 for all
    // sub-tiles (row offsets are multiples of 32/64), per-lane constant.
    const int lane31 = lane & 31;
    const int khalf  = lane >> 5;
    const int xr     = lane & 7;
    int koff[4];
#pragma unroll
    for (int ks = 0; ks < 4; ++ks) koff[ks] = ((ks * 2 + khalf) ^ xr) * 8;

    floatx16 acc[4][2] = {};   // [mi][nj]

    // Prologue: K0 fully (B0,B1,A0,A1) + K1 (B0,B1,A0) = 14 loads; wait K0.
    stage(B + (size_t)bn * DIM,               &lds[0][1][0][0]);
    stage(B + (size_t)(bn + 128) * DIM,       &lds[0][1][1][0]);
    stage(A + (size_t)bm * DIM,               &lds[0][0][0][0]);
    stage(A + (size_t)(bm + 128) * DIM,       &lds[0][0][1][0]);
    stage(B + (size_t)bn * DIM + BK,          &lds[1][1][0][0]);
    stage(B + (size_t)(bn + 128) * DIM + BK,  &lds[1][1][1][0]);
    stage(A + (size_t)bm * DIM + BK,          &lds[1][0][0][0]);
    // Drain s_cb/s_bnd ds_writes so loop lgkm counts see only fragment reads.
    asm volatile("s_waitcnt vmcnt(6) lgkmcnt(0)" ::: "memory");
    bar();

#pragma unroll 2
    for (int T = 0; T < NT; ++T) {
        const int s  = T & 1;
        const int ns = s ^ 1;
        const _Float16* Ar = &lds[s][0][am][0];
        const _Float16* Br = &lds[s][1][bh][0];
        const size_t k1 = (size_t)(T + 1) * BK;
        const size_t k2 = (size_t)(T + 2) * BK;

#define LDA8(mi_, ks_) (*(const half8*)(Ar + ((mi_) * 32 + lane31) * BK + koff[ks_]))
#define LDB8(nj_, ks_) (*(const half8*)(Br + (bro + (nj_) * 32 + lane31) * BK + koff[ks_]))

        half8 aF[2][4], bF[2][4];

        // ---------------- phase 1: tiles (mi=0..1, nj=0) ----------------
        if (T + 1 < NT) stage(A + (size_t)(bm + 128) * DIM + k1, &lds[ns][0][1][0]);
#pragma unroll
        for (int ks = 0; ks < 4; ++ks) { aF[0][ks] = LDA8(0, ks); aF[1][ks] = LDA8(1, ks); }
#pragma unroll
        for (int ks = 0; ks < 4; ++ks) bF[0][ks] = LDB8(0, ks);
        SB0();
        asm volatile("s_waitcnt lgkmcnt(8)" ::: "memory");   // smooth arrival
        bar();
        asm volatile("s_waitcnt lgkmcnt(0)" ::: "memory");
        SB0();
        __builtin_amdgcn_s_setprio(1);
#pragma unroll
        for (int ks = 0; ks < 4; ++ks) {
            acc[0][0] = MFMA32(aF[0][ks], bF[0][ks], acc[0][0]);
            acc[1][0] = MFMA32(aF[1][ks], bF[0][ks], acc[1][0]);
        }
        __builtin_amdgcn_s_setprio(0);
        bar();

        // ---------------- phase 2: tiles (mi=0..1, nj=1) ----------------
#pragma unroll
        for (int ks = 0; ks < 4; ++ks) bF[1][ks] = LDB8(1, ks);
        SB0();
        bar();
        asm volatile("s_waitcnt lgkmcnt(0)" ::: "memory");
        SB0();
        __builtin_amdgcn_s_setprio(1);
#pragma unroll
        for (int ks = 0; ks < 4; ++ks) {
            acc[0][1] = MFMA32(aF[0][ks], bF[1][ks], acc[0][1]);
            acc[1][1] = MFMA32(aF[1][ks], bF[1][ks], acc[1][1]);
        }
        __builtin_amdgcn_s_setprio(0);
        bar();

        // ---------------- phase 3: tiles (mi=2..3, nj=0) ----------------
        // B fully read by end of ph2 for ALL waves -> stage B(T+2) now.
        if (T + 2 < NT) {
            stage(B + (size_t)bn * DIM + k2,         &lds[s][1][0][0]);
            stage(B + (size_t)(bn + 128) * DIM + k2, &lds[s][1][1][0]);
        }
#pragma unroll
        for (int ks = 0; ks < 4; ++ks) { aF[0][ks] = LDA8(2, ks); aF[1][ks] = LDA8(3, ks); }
        SB0();
        bar();
        asm volatile("s_waitcnt lgkmcnt(0)" ::: "memory");
        SB0();
        __builtin_amdgcn_s_setprio(1);
#pragma unroll
        for (int ks = 0; ks < 4; ++ks) {
            acc[2][0] = MFMA32(aF[0][ks], bF[0][ks], acc[2][0]);
            acc[3][0] = MFMA32(aF[1][ks], bF[0][ks], acc[3][0]);
        }
        __builtin_amdgcn_s_setprio(0);
        bar();

        // ---------------- phase 4: tiles (mi=2..3, nj=1) ----------------
        // A reads done at ph3 -> stage A0(T+2). No ds_reads, no lgkm wait.
        if (T + 2 < NT) stage(A + (size_t)bm * DIM + k2, &lds[s][0][0][0]);
        bar();
        __builtin_amdgcn_s_setprio(1);
#pragma unroll
        for (int ks = 0; ks < 4; ++ks) {
            acc[2][1] = MFMA32(aF[0][ks], bF[1][ks], acc[2][1]);
            acc[3][1] = MFMA32(aF[1][ks], bF[1][ks], acc[3][1]);
        }
        __builtin_amdgcn_s_setprio(0);
        // Counted vmcnt ONCE per K-tile; drain only for the final tiles.
        if (T < NT - 2) asm volatile("s_waitcnt vmcnt(6)" ::: "memory");
        else            asm volatile("s_waitcnt vmcnt(0)" ::: "memory");
        bar();
#undef LDA8
#undef LDB8
    }

    // D layout (32x32, m74/m101-verified): col = lane&31,
    // row = (reg&3) + 8*(reg>>2) + 4*(lane>>5).
    if (QUANT) {
        float bnd[15];
#pragma unroll
        for (int b = 0; b < 15; ++b) bnd[b] = s_bnd[b];
#pragma unroll
        for (int mi = 0; mi < 4; ++mi) {
            const int gr0 = bm + wm + mi * 32 + 4 * khalf;
#pragma unroll
            for (int nj = 0; nj < 2; ++nj) {
                const int gc = bn + wn + nj * 32 + lane31;
#pragma unroll
                for (int r = 0; r < 16; ++r) {
                    const int row = gr0 + (r & 3) + 8 * (r >> 2);
                    const float v = acc[mi][nj][r];
                    int idx = 0;
#pragma unroll
                    for (int b = 0; b < 15; ++b) idx += (v > bnd[b]) ? 1 : 0;
                    Yq[(size_t)row * DIM + gc] = s_cb[idx];
                }
            }
        }
    } else {
#pragma unroll
        for (int mi = 0; mi < 4; ++mi) {
            const int gr0 = bm + wm + mi * 32 + 4 * khalf;
#pragma unroll
            for (int nj = 0; nj < 2; ++nj) {
                const int gc = bn + wn + nj * 32 + lane31;
#pragma unroll
                for (int r = 0; r < 16; ++r) {
                    const int row = gr0 + (r & 3) + 8 * (r >> 2);
                    C[(size_t)row * DIM + gc] = acc[mi][nj][r];
                }
            }
        }
    }
}

// x (fp32) -> f16, 4 elements/thread
__global__ void convert_f16(const float* __restrict__ in, _Float16* __restrict__ out)
{
    const size_t i = ((size_t)blockIdx.x * 256 + threadIdx.x) * 4;
    const float4 v = *(const float4*)(in + i);
    half4v h;
    h.x = (_Float16)v.x; h.y = (_Float16)v.y; h.z = (_Float16)v.z; h.w = (_Float16)v.w;
    *(half4v*)(out + i) = h;
}

// Pi (fp32) -> Pi_f16 (straight) and PiT_f16 (transposed).
__global__ void prep_pi(const float* __restrict__ Pi,
                        _Float16* __restrict__ Pif,
                        _Float16* __restrict__ PiT)
{
    __shared__ _Float16 tile[64][68];
    const int t  = threadIdx.x;
    const int r0 = t >> 4;
    const int c4 = (t & 15) * 4;
    const int y0 = blockIdx.y * 64;
    const int x0 = blockIdx.x * 64;
#pragma unroll
    for (int ii = 0; ii < 4; ++ii) {
        const int r = ii * 16 + r0;
        const float4 v = *(const float4*)(Pi + (size_t)(y0 + r) * DIM + x0 + c4);
        half4v h;
        h.x = (_Float16)v.x; h.y = (_Float16)v.y; h.z = (_Float16)v.z; h.w = (_Float16)v.w;
        *(half4v*)(Pif + (size_t)(y0 + r) * DIM + x0 + c4) = h;
        tile[c4 + 0][r] = h.x;
        tile[c4 + 1][r] = h.y;
        tile[c4 + 2][r] = h.z;
        tile[c4 + 3][r] = h.w;
    }
    __syncthreads();
#pragma unroll
    for (int ii = 0; ii < 4; ++ii) {
        const int c = ii * 16 + r0;
        *(half4v*)(PiT + (size_t)(x0 + c) * DIM + y0 + c4) = *(const half4v*)&tile[c][c4];
    }
}

extern "C" void kernel_launch(void* const* d_in, const int* in_sizes, int n_in,
                              void* d_out, int out_size, void* d_ws, size_t ws_size,
                              hipStream_t stream)
{
    (void)in_sizes; (void)n_in; (void)out_size; (void)ws_size;
    const float* x  = (const float*)d_in[0];
    const float* Pi = (const float*)d_in[1];
    const float* cb = (const float*)d_in[2];
    float* out = (float*)d_out;

    char* ws = (char*)d_ws;
    const size_t MB32 = (size_t)DIM * DIM * sizeof(_Float16);  // 32 MiB
    _Float16* xh  = (_Float16*)(ws);
    _Float16* pih = (_Float16*)(ws + MB32);
    _Float16* pit = (_Float16*)(ws + 2 * MB32);
    _Float16* yh  = (_Float16*)(ws + 3 * MB32);

    convert_f16<<<dim3(DIM * DIM / (256 * 4)), dim3(256), 0, stream>>>(x, xh);
    prep_pi<<<dim3(DIM / 64, DIM / 64), dim3(256), 0, stream>>>(Pi, pih, pit);

    // GEMM1: y = x @ Pi^T, fused Lloyd-Max quantize -> y_tilde (f16)
    gemm_bt<true><<<dim3(DIM / BM, DIM / BN), dim3(THREADS), 0, stream>>>(xh, pih, cb, yh, nullptr);
    // GEMM2: x_tilde = y_tilde @ Pi  ==  "bt" GEMM against PiT
    gemm_bt<false><<<dim3(DIM / BM, DIM / BN), dim3(THREADS), 0, stream>>>(yh, pit, cb, nullptr, out);
}

// Round 5
// 433.398 us; speedup vs baseline: 1.0810x; 1.0810x over previous
//
#include <hip/hip_runtime.h>

#define DIM 4096
#define BM 256
#define BN 256
#define BK 64
#define NT (DIM / BK)      // 64 K-tiles
#define THREADS 512        // 8 waves: 2 (M) x 4 (N)

typedef _Float16 half8 __attribute__((ext_vector_type(8)));
typedef _Float16 half4v __attribute__((ext_vector_type(4)));
typedef float floatx4 __attribute__((ext_vector_type(4)));

// Async global->LDS, 16B per lane. LDS dest is wave-uniform base + lane*16.
__device__ __forceinline__ void async_copy16(const _Float16* g, _Float16* l) {
    __builtin_amdgcn_global_load_lds(
        (const __attribute__((address_space(1))) void*)g,
        (__attribute__((address_space(3))) void*)l,
        16, 0, 0);
}

__device__ __forceinline__ void cfence() { asm volatile("" ::: "memory"); }
__device__ __forceinline__ void bar() { cfence(); __builtin_amdgcn_s_barrier(); cfence(); }
#define SB0() __builtin_amdgcn_sched_barrier(0)
#define MFMA16(a_, b_, c_) __builtin_amdgcn_mfma_f32_16x16x32_f16((a_), (b_), (c_), 0, 0, 0)

// 256x256 tile, BK=64, faithful m201 8-phase port: 16x16x32 MFMA, balanced
// 12/4/8/0 ds_reads per phase, counted vmcnt(6) once per K-tile, setprio
// around MFMA clusters. LDS: [dbuf][A/B][half(128x64)] = 128 KiB.
// 3-bit XOR swizzle (16B-chunk ^ (row&7)): 0 bank conflicts (r2/r3-verified).
// global_load_lds writes linearly -> global source pre-swizzled; ds_read
// applies the same involution (both-sides rule).
//
// Phases (per K-tile T, slot s=T&1; quadrants of each wave's 128x64 output):
//   ph1: reads bF(j=0,1)[4] + aF(i=0..3)[8]; stage A1(T+1)->lds[s^1];
//        lgkm(8); bar; lgkm(0); 16 MFMA (i0-3 x j0-1); bar
//   ph2: reads bF(j=2,3)[4]; bar; lgkm(0); 16 MFMA (i0-3 x j2-3); bar
//   ph3: reads aF(i=4..7)[8]; stage B0,B1(T+2)->lds[s] (B fully read @ph2);
//        bar; lgkm(0); 16 MFMA (i4-7 x j0-1); bar
//   ph4: stage A0(T+2)->lds[s] (A reads retired @ph3); bar;
//        16 MFMA (i4-7 x j2-3); vmcnt(6); bar
// vmcnt(6): 14 outstanding at tile end; retire 8 oldest = all of K(T+1);
// K(T+2) minus A1 (6 loads) stays in flight. Never drained mid-loop.
template <bool QUANT>
__global__ __launch_bounds__(THREADS, 2)
void gemm_bt(const _Float16* __restrict__ A,
             const _Float16* __restrict__ B,
             const float* __restrict__ cb,
             _Float16* __restrict__ Yq,
             float* __restrict__ C)
{
    __shared__ _Float16 lds[2][2][2][128 * BK];   // 128 KiB
    __shared__ float    s_bnd[15];
    __shared__ _Float16 s_cb[16];

    const int t    = threadIdx.x;
    const int lane = t & 63;
    const int wid  = t >> 6;            // 0..7
    const int wm   = (wid >> 2) * 128;  // wave M origin in tile
    const int wn   = (wid & 3) * 64;    // wave N origin in tile
    const int am   = wid >> 2;          // A half this wave reads
    const int bh   = (wid >> 1) & 1;    // B half this wave reads
    const int bro  = (wid & 1) * 64;    // row offset inside B half

    // XCD-aware bijective swizzle (nwg = 256, 256 % 8 == 0)
    const int bid = blockIdx.y * gridDim.x + blockIdx.x;
    const int swz = (bid & 7) * (256 / 8) + (bid >> 3);
    const int bm  = (swz & 15) * BM;
    const int bn  = (swz >> 4) * BN;

    if (QUANT) {
        if (t < 16) s_cb[t]  = (_Float16)cb[t];
        if (t < 15) s_bnd[t] = 0.5f * (cb[t] + cb[t + 1]);
    }

    // Staging: one 128x64 half-tile = 1024 16B chunks; thread t owns physical
    // chunks t and 512+t. Physical chunk p holds logical (row = p>>3,
    // col = (p&7) ^ ((p>>3)&7)) -> pre-swizzle the global source.
    const int pc0 = t, pc1 = 512 + t;
    const int goff0 = (pc0 >> 3) * DIM + ((pc0 & 7) ^ ((pc0 >> 3) & 7)) * 8;  // halves
    const int goff1 = (pc1 >> 3) * DIM + ((pc1 & 7) ^ ((pc1 >> 3) & 7)) * 8;

    auto stage = [&](const _Float16* srcrow0, _Float16* dst) {
        async_copy16(srcrow0 + goff0, dst + t * 8);
        async_copy16(srcrow0 + goff1, dst + (512 + t) * 8);
    };

    // MFMA 16x16x32 f16 fragment: elem[k = (lane>>4)*8 + j] of row (lane&15).
    // Swizzle inverse on read: physical col = (ks*4+kg) ^ (row&7); row&7 ==
    // frow&7 for all sub-tiles, so the XOR is a per-lane constant.
    const int frow  = lane & 15;
    const int kg    = lane >> 4;
    const int xr    = frow & 7;
    const int koff0 = ((0 + kg) ^ xr) * 8;   // ks = 0
    const int koff1 = ((4 + kg) ^ xr) * 8;   // ks = 1

    floatx4 acc[8][4] = {};

    // Prologue: K0 fully (B0,B1,A0,A1) + K1 (B0,B1,A0) = 14 loads; wait K0.
    stage(B + (size_t)bn * DIM,               &lds[0][1][0][0]);
    stage(B + (size_t)(bn + 128) * DIM,       &lds[0][1][1][0]);
    stage(A + (size_t)bm * DIM,               &lds[0][0][0][0]);
    stage(A + (size_t)(bm + 128) * DIM,       &lds[0][0][1][0]);
    stage(B + (size_t)bn * DIM + BK,          &lds[1][1][0][0]);
    stage(B + (size_t)(bn + 128) * DIM + BK,  &lds[1][1][1][0]);
    stage(A + (size_t)bm * DIM + BK,          &lds[1][0][0][0]);
    // Drain s_cb/s_bnd ds_writes so loop lgkm counts see only fragment reads.
    asm volatile("s_waitcnt vmcnt(6) lgkmcnt(0)" ::: "memory");
    bar();

#pragma unroll 2
    for (int T = 0; T < NT; ++T) {
        const int s  = T & 1;
        const int ns = s ^ 1;
        const _Float16* Ar = &lds[s][0][am][0];
        const _Float16* Br = &lds[s][1][bh][0];
        const size_t k1 = (size_t)(T + 1) * BK;
        const size_t k2 = (size_t)(T + 2) * BK;

#define LDA8(i_, ks_) (*(const half8*)(Ar + ((i_) * 16 + frow) * BK + ((ks_) ? koff1 : koff0)))
#define LDB8(j_, ks_) (*(const half8*)(Br + (bro + (j_) * 16 + frow) * BK + ((ks_) ? koff1 : koff0)))

        half8 aF[2][4], bF[2][4];

        // -------- phase 1: quadrant (i=0..3, j=0..1); 12 reads --------
        if (T + 1 < NT) stage(A + (size_t)(bm + 128) * DIM + k1, &lds[ns][0][1][0]);
        bF[0][0] = LDB8(0, 0); bF[1][0] = LDB8(0, 1);
        bF[0][1] = LDB8(1, 0); bF[1][1] = LDB8(1, 1);
#pragma unroll
        for (int i = 0; i < 4; ++i) { aF[0][i] = LDA8(i, 0); aF[1][i] = LDA8(i, 1); }
        SB0();
        asm volatile("s_waitcnt lgkmcnt(8)" ::: "memory");   // smooth arrival
        bar();
        asm volatile("s_waitcnt lgkmcnt(0)" ::: "memory");
        SB0();
        __builtin_amdgcn_s_setprio(1);
#pragma unroll
        for (int i = 0; i < 4; ++i)
#pragma unroll
            for (int j = 0; j < 2; ++j) {
                acc[i][j] = MFMA16(aF[0][i], bF[0][j], acc[i][j]);
                acc[i][j] = MFMA16(aF[1][i], bF[1][j], acc[i][j]);
            }
        __builtin_amdgcn_s_setprio(0);
        bar();

        // -------- phase 2: quadrant (i=0..3, j=2..3); 4 reads --------
        bF[0][2] = LDB8(2, 0); bF[1][2] = LDB8(2, 1);
        bF[0][3] = LDB8(3, 0); bF[1][3] = LDB8(3, 1);
        SB0();
        bar();
        asm volatile("s_waitcnt lgkmcnt(0)" ::: "memory");
        SB0();
        __builtin_amdgcn_s_setprio(1);
#pragma unroll
        for (int i = 0; i < 4; ++i)
#pragma unroll
            for (int j = 0; j < 2; ++j) {
                acc[i][2 + j] = MFMA16(aF[0][i], bF[0][2 + j], acc[i][2 + j]);
                acc[i][2 + j] = MFMA16(aF[1][i], bF[1][2 + j], acc[i][2 + j]);
            }
        __builtin_amdgcn_s_setprio(0);
        bar();

        // -------- phase 3: quadrant (i=4..7, j=0..1); 8 reads --------
        // B fully read by end of ph2 for ALL waves -> stage B(T+2) now.
        if (T + 2 < NT) {
            stage(B + (size_t)bn * DIM + k2,         &lds[s][1][0][0]);
            stage(B + (size_t)(bn + 128) * DIM + k2, &lds[s][1][1][0]);
        }
#pragma unroll
        for (int i = 0; i < 4; ++i) { aF[0][i] = LDA8(4 + i, 0); aF[1][i] = LDA8(4 + i, 1); }
        SB0();
        bar();
        asm volatile("s_waitcnt lgkmcnt(0)" ::: "memory");
        SB0();
        __builtin_amdgcn_s_setprio(1);
#pragma unroll
        for (int i = 0; i < 4; ++i)
#pragma unroll
            for (int j = 0; j < 2; ++j) {
                acc[4 + i][j] = MFMA16(aF[0][i], bF[0][j], acc[4 + i][j]);
                acc[4 + i][j] = MFMA16(aF[1][i], bF[1][j], acc[4 + i][j]);
            }
        __builtin_amdgcn_s_setprio(0);
        bar();

        // -------- phase 4: quadrant (i=4..7, j=2..3); 0 reads --------
        if (T + 2 < NT) stage(A + (size_t)bm * DIM + k2, &lds[s][0][0][0]);
        bar();
        __builtin_amdgcn_s_setprio(1);
#pragma unroll
        for (int i = 0; i < 4; ++i)
#pragma unroll
            for (int j = 0; j < 2; ++j) {
                acc[4 + i][2 + j] = MFMA16(aF[0][i], bF[0][2 + j], acc[4 + i][2 + j]);
                acc[4 + i][2 + j] = MFMA16(aF[1][i], bF[1][2 + j], acc[4 + i][2 + j]);
            }
        __builtin_amdgcn_s_setprio(0);
        // Counted vmcnt ONCE per K-tile; drain only for the final tiles.
        if (T < NT - 2) asm volatile("s_waitcnt vmcnt(6)" ::: "memory");
        else            asm volatile("s_waitcnt vmcnt(0)" ::: "memory");
        bar();
#undef LDA8
#undef LDB8
    }

    // D layout: col = lane&15, row = (lane>>4)*4 + reg  [m89-verified]
    if (QUANT) {
        float bnd[15];
#pragma unroll
        for (int b = 0; b < 15; ++b) bnd[b] = s_bnd[b];
#pragma unroll
        for (int i = 0; i < 8; ++i) {
            const int gr0 = bm + wm + i * 16 + (lane >> 4) * 4;
#pragma unroll
            for (int j = 0; j < 4; ++j) {
                const int gc = bn + wn + j * 16 + frow;
#pragma unroll
                for (int rr = 0; rr < 4; ++rr) {
                    const float v = acc[i][j][rr];
                    int idx = 0;
#pragma unroll
                    for (int b = 0; b < 15; ++b) idx += (v > bnd[b]) ? 1 : 0;
                    Yq[(size_t)(gr0 + rr) * DIM + gc] = s_cb[idx];
                }
            }
        }
    } else {
#pragma unroll
        for (int i = 0; i < 8; ++i) {
            const int gr0 = bm + wm + i * 16 + (lane >> 4) * 4;
#pragma unroll
            for (int j = 0; j < 4; ++j) {
                const int gc = bn + wn + j * 16 + frow;
#pragma unroll
                for (int rr = 0; rr < 4; ++rr)
                    C[(size_t)(gr0 + rr) * DIM + gc] = acc[i][j][rr];
            }
        }
    }
}

// x (fp32) -> f16, 4 elements/thread
__global__ void convert_f16(const float* __restrict__ in, _Float16* __restrict__ out)
{
    const size_t i = ((size_t)blockIdx.x * 256 + threadIdx.x) * 4;
    const float4 v = *(const float4*)(in + i);
    half4v h;
    h.x = (_Float16)v.x; h.y = (_Float16)v.y; h.z = (_Float16)v.z; h.w = (_Float16)v.w;
    *(half4v*)(out + i) = h;
}

// Pi (fp32) -> Pi_f16 (straight) and PiT_f16 (transposed).
__global__ void prep_pi(const float* __restrict__ Pi,
                        _Float16* __restrict__ Pif,
                        _Float16* __restrict__ PiT)
{
    __shared__ _Float16 tile[64][68];
    const int t  = threadIdx.x;
    const int r0 = t >> 4;
    const int c4 = (t & 15) * 4;
    const int y0 = blockIdx.y * 64;
    const int x0 = blockIdx.x * 64;
#pragma unroll
    for (int ii = 0; ii < 4; ++ii) {
        const int r = ii * 16 + r0;
        const float4 v = *(const float4*)(Pi + (size_t)(y0 + r) * DIM + x0 + c4);
        half4v h;
        h.x = (_Float16)v.x; h.y = (_Float16)v.y; h.z = (_Float16)v.z; h.w = (_Float16)v.w;
        *(half4v*)(Pif + (size_t)(y0 + r) * DIM + x0 + c4) = h;
        tile[c4 + 0][r] = h.x;
        tile[c4 + 1][r] = h.y;
        tile[c4 + 2][r] = h.z;
        tile[c4 + 3][r] = h.w;
    }
    __syncthreads();
#pragma unroll
    for (int ii = 0; ii < 4; ++ii) {
        const int c = ii * 16 + r0;
        *(half4v*)(PiT + (size_t)(x0 + c) * DIM + y0 + c4) = *(const half4v*)&tile[c][c4];
    }
}

extern "C" void kernel_launch(void* const* d_in, const int* in_sizes, int n_in,
                              void* d_out, int out_size, void* d_ws, size_t ws_size,
                              hipStream_t stream)
{
    (void)in_sizes; (void)n_in; (void)out_size; (void)ws_size;
    const float* x  = (const float*)d_in[0];
    const float* Pi = (const float*)d_in[1];
    const float* cb = (const float*)d_in[2];
    float* out = (float*)d_out;

    char* ws = (char*)d_ws;
    const size_t MB32 = (size_t)DIM * DIM * sizeof(_Float16);  // 32 MiB
    _Float16* xh  = (_Float16*)(ws);
    _Float16* pih = (_Float16*)(ws + MB32);
    _Float16* pit = (_Float16*)(ws + 2 * MB32);
    _Float16* yh  = (_Float16*)(ws + 3 * MB32);

    convert_f16<<<dim3(DIM * DIM / (256 * 4)), dim3(256), 0, stream>>>(x, xh);
    prep_pi<<<dim3(DIM / 64, DIM / 64), dim3(256), 0, stream>>>(Pi, pih, pit);

    // GEMM1: y = x @ Pi^T, fused Lloyd-Max quantize -> y_tilde (f16)
    gemm_bt<true><<<dim3(DIM / BM, DIM / BN), dim3(THREADS), 0, stream>>>(xh, pih, cb, yh, nullptr);
    // GEMM2: x_tilde = y_tilde @ Pi  ==  "bt" GEMM against PiT
    gemm_bt<false><<<dim3(DIM / BM, DIM / BN), dim3(THREADS), 0, stream>>>(yh, pit, cb, nullptr, out);
}

// Round 6
// 412.662 us; speedup vs baseline: 1.1354x; 1.0502x over previous
//
#include <hip/hip_runtime.h>

#define DIM 4096
#define BM 256
#define BN 256
#define BK 64
#define NT (DIM / BK)      // 64 K-tiles
#define THREADS 512        // 8 waves: 2 (M) x 4 (N)

typedef _Float16 half8 __attribute__((ext_vector_type(8)));
typedef _Float16 half4v __attribute__((ext_vector_type(4)));
typedef float floatx4 __attribute__((ext_vector_type(4)));

// Async global->LDS, 16B per lane. LDS dest is wave-uniform base + lane*16.
__device__ __forceinline__ void async_copy16(const _Float16* g, _Float16* l) {
    __builtin_amdgcn_global_load_lds(
        (const __attribute__((address_space(1))) void*)g,
        (__attribute__((address_space(3))) void*)l,
        16, 0, 0);
}

__device__ __forceinline__ void cfence() { asm volatile("" ::: "memory"); }
__device__ __forceinline__ void bar() { cfence(); __builtin_amdgcn_s_barrier(); cfence(); }

// 256x256 tile, BK=64, 8-phase schedule with counted vmcnt (r2 schedule,
// best timed 416.7 us). LDS: [dbuf][A/B][half(128x64)] = 128 KiB.
// 3-bit XOR swizzle (16B-chunk ^ (row&7)) -> 0 bank conflicts (r2-verified).
// global_load_lds writes linearly -> global source pre-swizzled; ds_read
// applies the same involution (both-sides rule).
//
// NEW this round: compact 4x8 per-XCD block chunking. Blocks with
// bid%8 == x land on XCD x; map each XCD's 32 blocks to a 4-row x 8-col
// rectangle of the 16x16 panel grid. Per-XCD beyond-L2 inflow drops from
// 16 A-panels + 2 B-panels = 36 MB (strip mapping) to 4 + 8 = 24 MB
// (-33% total: 288 -> 192 MB/GEMM), with 8-way concurrent A reuse and
// 4-way B reuse inside each XCD's L2.
template <bool QUANT>
__global__ __launch_bounds__(THREADS, 2)
void gemm_bt(const _Float16* __restrict__ A,
             const _Float16* __restrict__ B,
             const float* __restrict__ cb,
             _Float16* __restrict__ Yq,
             float* __restrict__ C)
{
    __shared__ _Float16 lds[2][2][2][128 * BK];   // 128 KiB
    __shared__ float    s_bnd[15];
    __shared__ _Float16 s_cb[16];

    const int t    = threadIdx.x;
    const int lane = t & 63;
    const int wid  = t >> 6;            // 0..7
    const int wm   = (wid >> 2) * 128;  // wave M origin in tile
    const int wn   = (wid & 3) * 64;    // wave N origin in tile
    const int am   = wid >> 2;          // A half this wave reads
    const int bh   = (wid >> 1) & 1;    // B half this wave reads
    const int bro  = (wid & 1) * 64;    // row offset inside B half
    const bool earlyB = (bh == 0);      // B-half0 overwritten at ph2 -> read all B in ph1

    // Compact 4x8 per-XCD chunking (bijective; 256 blocks, 8 XCDs x 32).
    const int bid = blockIdx.y * gridDim.x + blockIdx.x;
    const int xcd = bid & 7;
    const int jj  = bid >> 3;                      // 0..31 within XCD
    const int prow = (xcd >> 1) * 4 + (jj >> 3);   // 0..15 M-panel
    const int pcol = (xcd & 1) * 8 + (jj & 7);     // 0..15 N-panel
    const int bm  = prow * BM;
    const int bn  = pcol * BN;

    if (QUANT) {
        if (t < 16) s_cb[t]  = (_Float16)cb[t];
        if (t < 15) s_bnd[t] = 0.5f * (cb[t] + cb[t + 1]);
    }

    // Staging: one 128x64 half-tile = 1024 16B chunks; thread t owns physical
    // chunks t and 512+t. Physical chunk p holds logical (row = p>>3,
    // col = (p&7) ^ ((p>>3)&7)) -> pre-swizzle the global source.
    const int pc0 = t, pc1 = 512 + t;
    const int goff0 = (pc0 >> 3) * DIM + ((pc0 & 7) ^ ((pc0 >> 3) & 7)) * 8;  // halves
    const int goff1 = (pc1 >> 3) * DIM + ((pc1 & 7) ^ ((pc1 >> 3) & 7)) * 8;

    auto stage = [&](const _Float16* srcrow0, _Float16* dst) {
        async_copy16(srcrow0 + goff0, dst + t * 8);
        async_copy16(srcrow0 + goff1, dst + (512 + t) * 8);
    };

    // MFMA 16x16x32 f16 fragment: elem[k = (lane>>4)*8 + j] of row (lane&15).
    // Swizzle inverse on read: physical col = (ks*4+kg) ^ (row&7); row&7 ==
    // frow&7 for all sub-tiles, so the XOR is a per-lane constant.
    const int frow  = lane & 15;
    const int kg    = lane >> 4;
    const int xr    = frow & 7;
    const int koff0 = ((0 + kg) ^ xr) * 8;   // ks = 0
    const int koff1 = ((4 + kg) ^ xr) * 8;   // ks = 1

    floatx4 acc[8][4] = {};

    // Prologue: K0 fully (B0,B1,A0,A1) + K1 (B0,B1,A0) = 14 loads; wait K0.
    stage(B + (size_t)bn * DIM,               &lds[0][1][0][0]);
    stage(B + (size_t)(bn + 128) * DIM,       &lds[0][1][1][0]);
    stage(A + (size_t)bm * DIM,               &lds[0][0][0][0]);
    stage(A + (size_t)(bm + 128) * DIM,       &lds[0][0][1][0]);
    stage(B + (size_t)bn * DIM + BK,          &lds[1][1][0][0]);
    stage(B + (size_t)(bn + 128) * DIM + BK,  &lds[1][1][1][0]);
    stage(A + (size_t)bm * DIM + BK,          &lds[1][0][0][0]);
    asm volatile("s_waitcnt vmcnt(6)" ::: "memory");
    bar();

#pragma unroll 2
    for (int T = 0; T < NT; ++T) {
        const int s  = T & 1;
        const int ns = s ^ 1;
        const _Float16* Ar = &lds[s][0][am][0];
        const _Float16* Br = &lds[s][1][bh][0];
        const size_t k1 = (size_t)(T + 1) * BK;
        const size_t k2 = (size_t)(T + 2) * BK;

#define LDA8(i_, ks_) (*(const half8*)(Ar + ((i_) * 16 + frow) * BK + ((ks_) ? koff1 : koff0)))
#define LDB8(j_, ks_) (*(const half8*)(Br + (bro + (j_) * 16 + frow) * BK + ((ks_) ? koff1 : koff0)))

        half8 aF[2][4], bF[2][4];

        // ---------------- phase 1: quadrant (0,0) ----------------
#pragma unroll
        for (int i = 0; i < 4; ++i) { aF[0][i] = LDA8(i, 0); aF[1][i] = LDA8(i, 1); }
        bF[0][0] = LDB8(0, 0); bF[1][0] = LDB8(0, 1);
        bF[0][1] = LDB8(1, 0); bF[1][1] = LDB8(1, 1);
        if (earlyB) {   // must finish B-half0 before its ph2 overwrite
            bF[0][2] = LDB8(2, 0); bF[1][2] = LDB8(2, 1);
            bF[0][3] = LDB8(3, 0); bF[1][3] = LDB8(3, 1);
        }
        if (T + 1 < NT) stage(A + (size_t)(bm + 128) * DIM + k1, &lds[ns][0][1][0]);
        bar();
        asm volatile("s_waitcnt lgkmcnt(0)" ::: "memory");
        __builtin_amdgcn_sched_barrier(0);
        __builtin_amdgcn_s_setprio(1);
#pragma unroll
        for (int i = 0; i < 4; ++i)
#pragma unroll
            for (int j = 0; j < 2; ++j) {
                acc[i][j] = __builtin_amdgcn_mfma_f32_16x16x32_f16(aF[0][i], bF[0][j], acc[i][j], 0, 0, 0);
                acc[i][j] = __builtin_amdgcn_mfma_f32_16x16x32_f16(aF[1][i], bF[1][j], acc[i][j], 0, 0, 0);
            }
        __builtin_amdgcn_s_setprio(0);
        bar();

        // ---------------- phase 2: quadrant (0,1) ----------------
        if (!earlyB) {
            bF[0][2] = LDB8(2, 0); bF[1][2] = LDB8(2, 1);
            bF[0][3] = LDB8(3, 0); bF[1][3] = LDB8(3, 1);
        }
        if (T + 2 < NT) stage(B + (size_t)bn * DIM + k2, &lds[s][1][0][0]);
        bar();
        asm volatile("s_waitcnt lgkmcnt(0)" ::: "memory");
        __builtin_amdgcn_sched_barrier(0);
        __builtin_amdgcn_s_setprio(1);
#pragma unroll
        for (int i = 0; i < 4; ++i)
#pragma unroll
            for (int j = 0; j < 2; ++j) {
                acc[i][2 + j] = __builtin_amdgcn_mfma_f32_16x16x32_f16(aF[0][i], bF[0][2 + j], acc[i][2 + j], 0, 0, 0);
                acc[i][2 + j] = __builtin_amdgcn_mfma_f32_16x16x32_f16(aF[1][i], bF[1][2 + j], acc[i][2 + j], 0, 0, 0);
            }
        __builtin_amdgcn_s_setprio(0);
        bar();

        // ---------------- phase 3: quadrant (1,0) ----------------
#pragma unroll
        for (int i = 0; i < 4; ++i) { aF[0][i] = LDA8(4 + i, 0); aF[1][i] = LDA8(4 + i, 1); }
        if (T + 2 < NT) stage(B + (size_t)(bn + 128) * DIM + k2, &lds[s][1][1][0]);
        bar();
        asm volatile("s_waitcnt lgkmcnt(0)" ::: "memory");
        __builtin_amdgcn_sched_barrier(0);
        __builtin_amdgcn_s_setprio(1);
#pragma unroll
        for (int i = 0; i < 4; ++i)
#pragma unroll
            for (int j = 0; j < 2; ++j) {
                acc[4 + i][j] = __builtin_amdgcn_mfma_f32_16x16x32_f16(aF[0][i], bF[0][j], acc[4 + i][j], 0, 0, 0);
                acc[4 + i][j] = __builtin_amdgcn_mfma_f32_16x16x32_f16(aF[1][i], bF[1][j], acc[4 + i][j], 0, 0, 0);
            }
        __builtin_amdgcn_s_setprio(0);
        bar();

        // ---------------- phase 4: quadrant (1,1) ----------------
        if (T + 2 < NT) stage(A + (size_t)bm * DIM + k2, &lds[s][0][0][0]);
        bar();
        __builtin_amdgcn_s_setprio(1);
#pragma unroll
        for (int i = 0; i < 4; ++i)
#pragma unroll
            for (int j = 0; j < 2; ++j) {
                acc[4 + i][2 + j] = __builtin_amdgcn_mfma_f32_16x16x32_f16(aF[0][i], bF[0][2 + j], acc[4 + i][2 + j], 0, 0, 0);
                acc[4 + i][2 + j] = __builtin_amdgcn_mfma_f32_16x16x32_f16(aF[1][i], bF[1][2 + j], acc[4 + i][2 + j], 0, 0, 0);
            }
        __builtin_amdgcn_s_setprio(0);
        // Counted vmcnt ONCE per K-tile; drain only for the final tiles.
        if (T < NT - 2) asm volatile("s_waitcnt vmcnt(6)" ::: "memory");
        else            asm volatile("s_waitcnt vmcnt(0)" ::: "memory");
        bar();
#undef LDA8
#undef LDB8
    }

    // D layout: col = lane&15, row = (lane>>4)*4 + reg  [m89-verified]
    if (QUANT) {
        float bnd[15];
#pragma unroll
        for (int b = 0; b < 15; ++b) bnd[b] = s_bnd[b];
#pragma unroll
        for (int i = 0; i < 8; ++i) {
            const int gr0 = bm + wm + i * 16 + (lane >> 4) * 4;
#pragma unroll
            for (int j = 0; j < 4; ++j) {
                const int gc = bn + wn + j * 16 + frow;
#pragma unroll
                for (int rr = 0; rr < 4; ++rr) {
                    const float v = acc[i][j][rr];
                    int idx = 0;
#pragma unroll
                    for (int b = 0; b < 15; ++b) idx += (v > bnd[b]) ? 1 : 0;
                    Yq[(size_t)(gr0 + rr) * DIM + gc] = s_cb[idx];
                }
            }
        }
    } else {
#pragma unroll
        for (int i = 0; i < 8; ++i) {
            const int gr0 = bm + wm + i * 16 + (lane >> 4) * 4;
#pragma unroll
            for (int j = 0; j < 4; ++j) {
                const int gc = bn + wn + j * 16 + frow;
#pragma unroll
                for (int rr = 0; rr < 4; ++rr)
                    C[(size_t)(gr0 + rr) * DIM + gc] = acc[i][j][rr];
            }
        }
    }
}

// x (fp32) -> f16, 4 elements/thread
__global__ void convert_f16(const float* __restrict__ in, _Float16* __restrict__ out)
{
    const size_t i = ((size_t)blockIdx.x * 256 + threadIdx.x) * 4;
    const float4 v = *(const float4*)(in + i);
    half4v h;
    h.x = (_Float16)v.x; h.y = (_Float16)v.y; h.z = (_Float16)v.z; h.w = (_Float16)v.w;
    *(half4v*)(out + i) = h;
}

// Pi (fp32) -> Pi_f16 (straight) and PiT_f16 (transposed).
__global__ void prep_pi(const float* __restrict__ Pi,
                        _Float16* __restrict__ Pif,
                        _Float16* __restrict__ PiT)
{
    __shared__ _Float16 tile[64][68];
    const int t  = threadIdx.x;
    const int r0 = t >> 4;
    const int c4 = (t & 15) * 4;
    const int y0 = blockIdx.y * 64;
    const int x0 = blockIdx.x * 64;
#pragma unroll
    for (int ii = 0; ii < 4; ++ii) {
        const int r = ii * 16 + r0;
        const float4 v = *(const float4*)(Pi + (size_t)(y0 + r) * DIM + x0 + c4);
        half4v h;
        h.x = (_Float16)v.x; h.y = (_Float16)v.y; h.z = (_Float16)v.z; h.w = (_Float16)v.w;
        *(half4v*)(Pif + (size_t)(y0 + r) * DIM + x0 + c4) = h;
        tile[c4 + 0][r] = h.x;
        tile[c4 + 1][r] = h.y;
        tile[c4 + 2][r] = h.z;
        tile[c4 + 3][r] = h.w;
    }
    __syncthreads();
#pragma unroll
    for (int ii = 0; ii < 4; ++ii) {
        const int c = ii * 16 + r0;
        *(half4v*)(PiT + (size_t)(x0 + c) * DIM + y0 + c4) = *(const half4v*)&tile[c][c4];
    }
}

extern "C" void kernel_launch(void* const* d_in, const int* in_sizes, int n_in,
                              void* d_out, int out_size, void* d_ws, size_t ws_size,
                              hipStream_t stream)
{
    (void)in_sizes; (void)n_in; (void)out_size; (void)ws_size;
    const float* x  = (const float*)d_in[0];
    const float* Pi = (const float*)d_in[1];
    const float* cb = (const float*)d_in[2];
    float* out = (float*)d_out;

    char* ws = (char*)d_ws;
    const size_t MB32 = (size_t)DIM * DIM * sizeof(_Float16);  // 32 MiB
    _Float16* xh  = (_Float16*)(ws);
    _Float16* pih = (_Float16*)(ws + MB32);
    _Float16* pit = (_Float16*)(ws + 2 * MB32);
    _Float16* yh  = (_Float16*)(ws + 3 * MB32);

    convert_f16<<<dim3(DIM * DIM / (256 * 4)), dim3(256), 0, stream>>>(x, xh);
    prep_pi<<<dim3(DIM / 64, DIM / 64), dim3(256), 0, stream>>>(Pi, pih, pit);

    // GEMM1: y = x @ Pi^T, fused Lloyd-Max quantize -> y_tilde (f16)
    gemm_bt<true><<<dim3(DIM / BM, DIM / BN), dim3(THREADS), 0, stream>>>(xh, pih, cb, yh, nullptr);
    // GEMM2: x_tilde = y_tilde @ Pi  ==  "bt" GEMM against PiT
    gemm_bt<false><<<dim3(DIM / BM, DIM / BN), dim3(THREADS), 0, stream>>>(yh, pit, cb, nullptr, out);
}

// Round 7
// 408.268 us; speedup vs baseline: 1.1476x; 1.0108x over previous
//
#include <hip/hip_runtime.h>

#define DIM 4096
#define BM 256
#define BN 256
#define BK 64
#define NT (DIM / BK)      // 64 K-tiles
#define THREADS 512        // 8 waves: 2 (M) x 4 (N)

typedef _Float16 half8 __attribute__((ext_vector_type(8)));
typedef _Float16 half4v __attribute__((ext_vector_type(4)));
typedef float floatx4 __attribute__((ext_vector_type(4)));

// Async global->LDS, 16B per lane. LDS dest is wave-uniform base + lane*16.
__device__ __forceinline__ void async_copy16(const _Float16* g, _Float16* l) {
    __builtin_amdgcn_global_load_lds(
        (const __attribute__((address_space(1))) void*)g,
        (__attribute__((address_space(3))) void*)l,
        16, 0, 0);
}

__device__ __forceinline__ void cfence() { asm volatile("" ::: "memory"); }
__device__ __forceinline__ void bar() { cfence(); __builtin_amdgcn_s_barrier(); cfence(); }

// 256x256 tile, BK=64, 8-phase schedule with counted vmcnt (r2 schedule).
// LDS: [dbuf][A/B][half(128x64)] = 128 KiB.
// 3-bit XOR swizzle (16B-chunk ^ (row&7)) -> 0 bank conflicts (r2/r6-verified).
// global_load_lds writes linearly -> global source pre-swizzled; ds_read
// applies the same involution (both-sides rule).
// Compact 4x8 per-XCD block chunking (r6-verified: FETCH 147.9 -> 98.7 MB).
template <bool QUANT>
__global__ __launch_bounds__(THREADS, 2)
void gemm_bt(const _Float16* __restrict__ A,
             const _Float16* __restrict__ B,
             const float* __restrict__ cb,
             _Float16* __restrict__ Yq,
             float* __restrict__ C)
{
    __shared__ _Float16 lds[2][2][2][128 * BK];   // 128 KiB
    __shared__ float    s_bnd[15];
    __shared__ _Float16 s_cb[16];

    const int t    = threadIdx.x;
    const int lane = t & 63;
    const int wid  = t >> 6;            // 0..7
    const int wm   = (wid >> 2) * 128;  // wave M origin in tile
    const int wn   = (wid & 3) * 64;    // wave N origin in tile
    const int am   = wid >> 2;          // A half this wave reads
    const int bh   = (wid >> 1) & 1;    // B half this wave reads
    const int bro  = (wid & 1) * 64;    // row offset inside B half
    const bool earlyB = (bh == 0);      // B-half0 overwritten at ph2 -> read all B in ph1

    // Compact 4x8 per-XCD chunking (bijective; 256 blocks, 8 XCDs x 32).
    const int bid = blockIdx.y * gridDim.x + blockIdx.x;
    const int xcd = bid & 7;
    const int jj  = bid >> 3;                      // 0..31 within XCD
    const int prow = (xcd >> 1) * 4 + (jj >> 3);   // 0..15 M-panel
    const int pcol = (xcd & 1) * 8 + (jj & 7);     // 0..15 N-panel
    const int bm  = prow * BM;
    const int bn  = pcol * BN;

    if (QUANT) {
        if (t < 16) s_cb[t]  = (_Float16)cb[t];
        if (t < 15) s_bnd[t] = 0.5f * (cb[t] + cb[t + 1]);
    }

    // Staging: one 128x64 half-tile = 1024 16B chunks; thread t owns physical
    // chunks t and 512+t. Physical chunk p holds logical (row = p>>3,
    // col = (p&7) ^ ((p>>3)&7)) -> pre-swizzle the global source.
    const int pc0 = t, pc1 = 512 + t;
    const int goff0 = (pc0 >> 3) * DIM + ((pc0 & 7) ^ ((pc0 >> 3) & 7)) * 8;  // halves
    const int goff1 = (pc1 >> 3) * DIM + ((pc1 & 7) ^ ((pc1 >> 3) & 7)) * 8;

    auto stage = [&](const _Float16* srcrow0, _Float16* dst) {
        async_copy16(srcrow0 + goff0, dst + t * 8);
        async_copy16(srcrow0 + goff1, dst + (512 + t) * 8);
    };

    // MFMA 16x16x32 f16 fragment: elem[k = (lane>>4)*8 + j] of row (lane&15).
    // Swizzle inverse on read: physical col = (ks*4+kg) ^ (row&7); row&7 ==
    // frow&7 for all sub-tiles, so the XOR is a per-lane constant.
    const int frow  = lane & 15;
    const int kg    = lane >> 4;
    const int xr    = frow & 7;
    const int koff0 = ((0 + kg) ^ xr) * 8;   // ks = 0
    const int koff1 = ((4 + kg) ^ xr) * 8;   // ks = 1

    floatx4 acc[8][4] = {};

    // Prologue: K0 fully (B0,B1,A0,A1) + K1 (B0,B1,A0) = 14 loads; wait K0.
    stage(B + (size_t)bn * DIM,               &lds[0][1][0][0]);
    stage(B + (size_t)(bn + 128) * DIM,       &lds[0][1][1][0]);
    stage(A + (size_t)bm * DIM,               &lds[0][0][0][0]);
    stage(A + (size_t)(bm + 128) * DIM,       &lds[0][0][1][0]);
    stage(B + (size_t)bn * DIM + BK,          &lds[1][1][0][0]);
    stage(B + (size_t)(bn + 128) * DIM + BK,  &lds[1][1][1][0]);
    stage(A + (size_t)bm * DIM + BK,          &lds[1][0][0][0]);
    asm volatile("s_waitcnt vmcnt(6)" ::: "memory");
    bar();

#pragma unroll 2
    for (int T = 0; T < NT; ++T) {
        const int s  = T & 1;
        const int ns = s ^ 1;
        const _Float16* Ar = &lds[s][0][am][0];
        const _Float16* Br = &lds[s][1][bh][0];
        const size_t k1 = (size_t)(T + 1) * BK;
        const size_t k2 = (size_t)(T + 2) * BK;

#define LDA8(i_, ks_) (*(const half8*)(Ar + ((i_) * 16 + frow) * BK + ((ks_) ? koff1 : koff0)))
#define LDB8(j_, ks_) (*(const half8*)(Br + (bro + (j_) * 16 + frow) * BK + ((ks_) ? koff1 : koff0)))

        half8 aF[2][4], bF[2][4];

        // ---------------- phase 1: quadrant (0,0) ----------------
#pragma unroll
        for (int i = 0; i < 4; ++i) { aF[0][i] = LDA8(i, 0); aF[1][i] = LDA8(i, 1); }
        bF[0][0] = LDB8(0, 0); bF[1][0] = LDB8(0, 1);
        bF[0][1] = LDB8(1, 0); bF[1][1] = LDB8(1, 1);
        if (earlyB) {   // must finish B-half0 before its ph2 overwrite
            bF[0][2] = LDB8(2, 0); bF[1][2] = LDB8(2, 1);
            bF[0][3] = LDB8(3, 0); bF[1][3] = LDB8(3, 1);
        }
        if (T + 1 < NT) stage(A + (size_t)(bm + 128) * DIM + k1, &lds[ns][0][1][0]);
        bar();
        asm volatile("s_waitcnt lgkmcnt(0)" ::: "memory");
        __builtin_amdgcn_sched_barrier(0);
        __builtin_amdgcn_s_setprio(1);
#pragma unroll
        for (int i = 0; i < 4; ++i)
#pragma unroll
            for (int j = 0; j < 2; ++j) {
                acc[i][j] = __builtin_amdgcn_mfma_f32_16x16x32_f16(aF[0][i], bF[0][j], acc[i][j], 0, 0, 0);
                acc[i][j] = __builtin_amdgcn_mfma_f32_16x16x32_f16(aF[1][i], bF[1][j], acc[i][j], 0, 0, 0);
            }
        __builtin_amdgcn_s_setprio(0);
        bar();

        // ---------------- phase 2: quadrant (0,1) ----------------
        if (!earlyB) {
            bF[0][2] = LDB8(2, 0); bF[1][2] = LDB8(2, 1);
            bF[0][3] = LDB8(3, 0); bF[1][3] = LDB8(3, 1);
        }
        if (T + 2 < NT) stage(B + (size_t)bn * DIM + k2, &lds[s][1][0][0]);
        bar();
        asm volatile("s_waitcnt lgkmcnt(0)" ::: "memory");
        __builtin_amdgcn_sched_barrier(0);
        __builtin_amdgcn_s_setprio(1);
#pragma unroll
        for (int i = 0; i < 4; ++i)
#pragma unroll
            for (int j = 0; j < 2; ++j) {
                acc[i][2 + j] = __builtin_amdgcn_mfma_f32_16x16x32_f16(aF[0][i], bF[0][2 + j], acc[i][2 + j], 0, 0, 0);
                acc[i][2 + j] = __builtin_amdgcn_mfma_f32_16x16x32_f16(aF[1][i], bF[1][2 + j], acc[i][2 + j], 0, 0, 0);
            }
        __builtin_amdgcn_s_setprio(0);
        bar();

        // ---------------- phase 3: quadrant (1,0) ----------------
#pragma unroll
        for (int i = 0; i < 4; ++i) { aF[0][i] = LDA8(4 + i, 0); aF[1][i] = LDA8(4 + i, 1); }
        if (T + 2 < NT) stage(B + (size_t)(bn + 128) * DIM + k2, &lds[s][1][1][0]);
        bar();
        asm volatile("s_waitcnt lgkmcnt(0)" ::: "memory");
        __builtin_amdgcn_sched_barrier(0);
        __builtin_amdgcn_s_setprio(1);
#pragma unroll
        for (int i = 0; i < 4; ++i)
#pragma unroll
            for (int j = 0; j < 2; ++j) {
                acc[4 + i][j] = __builtin_amdgcn_mfma_f32_16x16x32_f16(aF[0][i], bF[0][j], acc[4 + i][j], 0, 0, 0);
                acc[4 + i][j] = __builtin_amdgcn_mfma_f32_16x16x32_f16(aF[1][i], bF[1][j], acc[4 + i][j], 0, 0, 0);
            }
        __builtin_amdgcn_s_setprio(0);
        bar();

        // ---------------- phase 4: quadrant (1,1) ----------------
        if (T + 2 < NT) stage(A + (size_t)bm * DIM + k2, &lds[s][0][0][0]);
        bar();
        __builtin_amdgcn_s_setprio(1);
#pragma unroll
        for (int i = 0; i < 4; ++i)
#pragma unroll
            for (int j = 0; j < 2; ++j) {
                acc[4 + i][2 + j] = __builtin_amdgcn_mfma_f32_16x16x32_f16(aF[0][i], bF[0][2 + j], acc[4 + i][2 + j], 0, 0, 0);
                acc[4 + i][2 + j] = __builtin_amdgcn_mfma_f32_16x16x32_f16(aF[1][i], bF[1][2 + j], acc[4 + i][2 + j], 0, 0, 0);
            }
        __builtin_amdgcn_s_setprio(0);
        // Counted vmcnt ONCE per K-tile; drain only for the final tiles.
        if (T < NT - 2) asm volatile("s_waitcnt vmcnt(6)" ::: "memory");
        else            asm volatile("s_waitcnt vmcnt(0)" ::: "memory");
        bar();
#undef LDA8
#undef LDB8
    }

    // D layout: col = lane&15, row = (lane>>4)*4 + reg  [m89-verified]
    if (QUANT) {
        float bnd[15];
#pragma unroll
        for (int b = 0; b < 15; ++b) bnd[b] = s_bnd[b];
#pragma unroll
        for (int i = 0; i < 8; ++i) {
            const int gr0 = bm + wm + i * 16 + (lane >> 4) * 4;
#pragma unroll
            for (int j = 0; j < 4; ++j) {
                const int gc = bn + wn + j * 16 + frow;
#pragma unroll
                for (int rr = 0; rr < 4; ++rr) {
                    const float v = acc[i][j][rr];
                    int idx = 0;
#pragma unroll
                    for (int b = 0; b < 15; ++b) idx += (v > bnd[b]) ? 1 : 0;
                    Yq[(size_t)(gr0 + rr) * DIM + gc] = s_cb[idx];
                }
            }
        }
    } else {
#pragma unroll
        for (int i = 0; i < 8; ++i) {
            const int gr0 = bm + wm + i * 16 + (lane >> 4) * 4;
#pragma unroll
            for (int j = 0; j < 4; ++j) {
                const int gc = bn + wn + j * 16 + frow;
#pragma unroll
                for (int rr = 0; rr < 4; ++rr)
                    C[(size_t)(gr0 + rr) * DIM + gc] = acc[i][j][rr];
            }
        }
    }
}

// Fused prep: one launch does BOTH Pi->f16 (straight + transposed) and
// x->f16. Blocks [0, 4096): Pi 64x64 tiles; blocks [4096, 12288): x convert
// (8 f32->f16 per thread, 16B stores). The two halves are independent
// streaming work; fusing removes one launch gap and runs them concurrently.
__global__ void prep_all(const float* __restrict__ Pi,
                         _Float16* __restrict__ Pif,
                         _Float16* __restrict__ PiT,
                         const float* __restrict__ x,
                         _Float16* __restrict__ xh)
{
    const int b = blockIdx.x;
    const int t = threadIdx.x;

    if (b >= 4096) {
        // ---- x -> f16, 8 elements/thread ----
        const size_t i = ((size_t)(b - 4096) * 256 + t) * 8;
        const float4 v0 = *(const float4*)(x + i);
        const float4 v1 = *(const float4*)(x + i + 4);
        half8 h;
        h[0] = (_Float16)v0.x; h[1] = (_Float16)v0.y;
        h[2] = (_Float16)v0.z; h[3] = (_Float16)v0.w;
        h[4] = (_Float16)v1.x; h[5] = (_Float16)v1.y;
        h[6] = (_Float16)v1.z; h[7] = (_Float16)v1.w;
        *(half8*)(xh + i) = h;
        return;
    }

    // ---- Pi tile: straight f16 + transposed f16 ----
    __shared__ _Float16 tile[64][68];
    const int r0 = t >> 4;          // 0..15
    const int c4 = (t & 15) * 4;    // 0..60
    const int y0 = (b >> 6) * 64;   // global row origin
    const int x0 = (b & 63) * 64;   // global col origin
#pragma unroll
    for (int ii = 0; ii < 4; ++ii) {
        const int r = ii * 16 + r0;
        const float4 v = *(const float4*)(Pi + (size_t)(y0 + r) * DIM + x0 + c4);
        half4v h;
        h.x = (_Float16)v.x; h.y = (_Float16)v.y; h.z = (_Float16)v.z; h.w = (_Float16)v.w;
        *(half4v*)(Pif + (size_t)(y0 + r) * DIM + x0 + c4) = h;
        tile[c4 + 0][r] = h.x;
        tile[c4 + 1][r] = h.y;
        tile[c4 + 2][r] = h.z;
        tile[c4 + 3][r] = h.w;
    }
    __syncthreads();
#pragma unroll
    for (int ii = 0; ii < 4; ++ii) {
        const int c = ii * 16 + r0;   // tile column = PiT row offset
        *(half4v*)(PiT + (size_t)(x0 + c) * DIM + y0 + c4) = *(const half4v*)&tile[c][c4];
    }
}

extern "C" void kernel_launch(void* const* d_in, const int* in_sizes, int n_in,
                              void* d_out, int out_size, void* d_ws, size_t ws_size,
                              hipStream_t stream)
{
    (void)in_sizes; (void)n_in; (void)out_size; (void)ws_size;
    const float* x  = (const float*)d_in[0];
    const float* Pi = (const float*)d_in[1];
    const float* cb = (const float*)d_in[2];
    float* out = (float*)d_out;

    char* ws = (char*)d_ws;
    const size_t MB32 = (size_t)DIM * DIM * sizeof(_Float16);  // 32 MiB
    _Float16* xh  = (_Float16*)(ws);
    _Float16* pih = (_Float16*)(ws + MB32);
    _Float16* pit = (_Float16*)(ws + 2 * MB32);
    _Float16* yh  = (_Float16*)(ws + 3 * MB32);

    // Fused prep: 4096 Pi-tile blocks + 8192 x-convert blocks.
    prep_all<<<dim3(4096 + 8192), dim3(256), 0, stream>>>(Pi, pih, pit, x, xh);

    // GEMM1: y = x @ Pi^T, fused Lloyd-Max quantize -> y_tilde (f16)
    gemm_bt<true><<<dim3(DIM / BM, DIM / BN), dim3(THREADS), 0, stream>>>(xh, pih, cb, yh, nullptr);
    // GEMM2: x_tilde = y_tilde @ Pi  ==  "bt" GEMM against PiT
    gemm_bt<false><<<dim3(DIM / BM, DIM / BN), dim3(THREADS), 0, stream>>>(yh, pit, cb, nullptr, out);
}